// Round 5
// baseline (1274.091 us; speedup 1.0000x reference)
//
#include <hip/hip_runtime.h>

// Problem constants (match reference)
static constexpr int DIM = 128;
static constexpr int N = DIM * DIM * DIM;        // 2,097,152 voxels
static constexpr int ITERS = 20;
static constexpr float EPS = 1e-6f;

// Gaussian(sigma=1, radius=3) normalized weights
#define W0 0.39905028f
#define W1 0.24203624f
#define W2 0.05400559f
#define W3 0.00443305f

__device__ __forceinline__ int clamp_i(int v, int lo, int hi) {
    return min(max(v, lo), hi);
}

// ---------------------------------------------------------------------------
// Trilinear warp, 4 voxels/thread: out[z,y,x] = mov sampled at (z+vf0, y+vf1,
// x+vf2), map_coordinates order=1 mode='nearest' (clamped indices).
// ---------------------------------------------------------------------------
__global__ __launch_bounds__(256) void warp_kernel(const float* __restrict__ mov,
                                                   const float* __restrict__ vf,
                                                   float* __restrict__ out) {
    int t = blockIdx.x * 256 + threadIdx.x;
    if (t >= N / 4) return;
    int idx = t << 2;
    int x0 = idx & 127, y = (idx >> 7) & 127, z = idx >> 14;

    float4 vz4 = *(const float4*)(vf + idx);
    float4 vy4 = *(const float4*)(vf + N + idx);
    float4 vx4 = *(const float4*)(vf + 2 * N + idx);
    float vzv[4] = {vz4.x, vz4.y, vz4.z, vz4.w};
    float vyv[4] = {vy4.x, vy4.y, vy4.z, vy4.w};
    float vxv[4] = {vx4.x, vx4.y, vx4.z, vx4.w};

    float o[4];
#pragma unroll
    for (int i = 0; i < 4; ++i) {
        float cz = (float)z + vzv[i];
        float cy = (float)y + vyv[i];
        float cx = (float)(x0 + i) + vxv[i];

        float flz = floorf(cz), fly = floorf(cy), flx = floorf(cx);
        float fz = cz - flz, fy = cy - fly, fx = cx - flx;

        int z0 = (int)flz, y0 = (int)fly, xx0 = (int)flx;
        int z0c = clamp_i(z0, 0, DIM - 1), z1c = clamp_i(z0 + 1, 0, DIM - 1);
        int y0c = clamp_i(y0, 0, DIM - 1), y1c = clamp_i(y0 + 1, 0, DIM - 1);
        int x0c = clamp_i(xx0, 0, DIM - 1), x1c = clamp_i(xx0 + 1, 0, DIM - 1);

        int b00 = (z0c << 14) + (y0c << 7);
        int b01 = (z0c << 14) + (y1c << 7);
        int b10 = (z1c << 14) + (y0c << 7);
        int b11 = (z1c << 14) + (y1c << 7);

        float v000 = mov[b00 + x0c], v001 = mov[b00 + x1c];
        float v010 = mov[b01 + x0c], v011 = mov[b01 + x1c];
        float v100 = mov[b10 + x0c], v101 = mov[b10 + x1c];
        float v110 = mov[b11 + x0c], v111 = mov[b11 + x1c];

        float c00 = v000 + fx * (v001 - v000);
        float c01 = v010 + fx * (v011 - v010);
        float c10 = v100 + fx * (v101 - v100);
        float c11 = v110 + fx * (v111 - v110);
        float c0 = c00 + fy * (c01 - c00);
        float c1 = c10 + fy * (c11 - c10);
        o[i] = c0 + fz * (c1 - c0);
    }
    *(float4*)(out + idx) = make_float4(o[0], o[1], o[2], o[3]);
}

// ---------------------------------------------------------------------------
// Fused forces + x-blur + y-blur. One block per (channel, z-plane, 32-row
// y-strip). Stage A computes u_c = vf_c + s*g_c for the 38-row halo strip
// into LDS S1 (forces recompute amp 1.19x, inputs L2-served). Stage B x-blur
// S1->S2. Stage C y-blur S2 -> global u2. Never materializes u.
// FIRST=true: vf==0, wpd==mov (iteration 1; also makes memset unnecessary).
// LDS 2*19456 = 38912 B -> 4 blocks/CU.
// ---------------------------------------------------------------------------
template <bool FIRST>
__global__ __launch_bounds__(256) void forces_xy_kernel(const float* __restrict__ wpd,
                                                        const float* __restrict__ fix,
                                                        const float* __restrict__ vf,
                                                        float* __restrict__ u2) {
    int b = blockIdx.x;
    int c = b >> 9;               // channel (512 blocks per channel)
    int t = b & 511;
    int z = t & 127;
    int y0 = (t >> 7) << 5;       // 0,32,64,96

    __shared__ float S1[38 * 128];
    __shared__ float S2[38 * 128];

    const float* vfc = vf + (size_t)c * N;

    // Stage A: forces -> u_c for rows y0-3 .. y0+34 into S1
    for (int e = threadIdx.x; e < 38 * 32; e += 256) {
        int x4 = e & 31;
        int r  = e >> 5;
        int gy = y0 + r - 3;
        float4 res = make_float4(0.0f, 0.0f, 0.0f, 0.0f);
        if (gy >= 0 && gy < 128) {
            int idx = (z << 14) + (gy << 7) + (x4 << 2);
            int xb = x4 << 2;

            float4 wc4 = *(const float4*)(wpd + idx);
            float4 fc4 = *(const float4*)(fix + idx);

            int iyp = (gy < 127) ? idx + 128   : idx;
            int iym = (gy > 0)   ? idx - 128   : idx;
            int izp = (z < 127)  ? idx + 16384 : idx;
            int izm = (z > 0)    ? idx - 16384 : idx;

            float4 wyp = *(const float4*)(wpd + iyp), wym = *(const float4*)(wpd + iym);
            float4 wzp = *(const float4*)(wpd + izp), wzm = *(const float4*)(wpd + izm);
            float4 fyp = *(const float4*)(fix + iyp), fym = *(const float4*)(fix + iym);
            float4 fzp = *(const float4*)(fix + izp), fzm = *(const float4*)(fix + izm);

            float wl = (xb > 0)   ? wpd[idx - 1] : 0.0f;
            float wr = (xb < 124) ? wpd[idx + 4] : 0.0f;
            float fl = (xb > 0)   ? fix[idx - 1] : 0.0f;
            float fr = (xb < 124) ? fix[idx + 4] : 0.0f;

            float wcv[4] = {wc4.x, wc4.y, wc4.z, wc4.w};
            float fcv[4] = {fc4.x, fc4.y, fc4.z, fc4.w};
            float wypv[4] = {wyp.x, wyp.y, wyp.z, wyp.w};
            float wymv[4] = {wym.x, wym.y, wym.z, wym.w};
            float wzpv[4] = {wzp.x, wzp.y, wzp.z, wzp.w};
            float wzmv[4] = {wzm.x, wzm.y, wzm.z, wzm.w};
            float fypv[4] = {fyp.x, fyp.y, fyp.z, fyp.w};
            float fymv[4] = {fym.x, fym.y, fym.z, fym.w};
            float fzpv[4] = {fzp.x, fzp.y, fzp.z, fzp.w};
            float fzmv[4] = {fzm.x, fzm.y, fzm.z, fzm.w};

            float4 vc4 = FIRST ? make_float4(0, 0, 0, 0)
                               : *(const float4*)(vfc + idx);
            float vcv[4] = {vc4.x, vc4.y, vc4.z, vc4.w};

            float ov[4];
#pragma unroll
            for (int i = 0; i < 4; ++i) {
                float wc = wcv[i], fc = fcv[i];
                float diff = wc - fc;

                float gwz = (z == 0)   ? (wzpv[i] - wc)
                          : (z == 127) ? (wc - wzmv[i])
                          : 0.5f * (wzpv[i] - wzmv[i]);
                float gfz = (z == 0)   ? (fzpv[i] - fc)
                          : (z == 127) ? (fc - fzmv[i])
                          : 0.5f * (fzpv[i] - fzmv[i]);
                float grz = 0.5f * (gwz + gfz);

                float gwy = (gy == 0)   ? (wypv[i] - wc)
                          : (gy == 127) ? (wc - wymv[i])
                          : 0.5f * (wypv[i] - wymv[i]);
                float gfy = (gy == 0)   ? (fypv[i] - fc)
                          : (gy == 127) ? (fc - fymv[i])
                          : 0.5f * (fypv[i] - fymv[i]);
                float gry = 0.5f * (gwy + gfy);

                float wleft  = (i == 0) ? wl : wcv[i - 1];
                float wright = (i == 3) ? wr : wcv[i + 1];
                float fleft  = (i == 0) ? fl : fcv[i - 1];
                float fright = (i == 3) ? fr : fcv[i + 1];
                int xi = xb + i;
                float gwx = (xi == 0)   ? (wright - wc)
                          : (xi == 127) ? (wc - wleft)
                          : 0.5f * (wright - wleft);
                float gfx = (xi == 0)   ? (fright - fc)
                          : (xi == 127) ? (fc - fleft)
                          : 0.5f * (fright - fleft);
                float grx = 0.5f * (gwx + gfx);

                float denom = grz * grz + gry * gry + grx * grx + diff * diff;
                float s = (denom > EPS) ? (diff / denom) : 0.0f;
                float g = (c == 0) ? grz : (c == 1) ? gry : grx;
                ov[i] = vcv[i] + s * g;
            }
            res = make_float4(ov[0], ov[1], ov[2], ov[3]);
        }
        *(float4*)(S1 + (r << 7) + (x4 << 2)) = res;
    }
    __syncthreads();

    // Stage B: x-blur S1 -> S2
    for (int e = threadIdx.x; e < 38 * 32; e += 256) {
        int x4 = e & 31;
        int r  = e >> 5;
        const float* base = S1 + (r << 7) + (x4 << 2);
        float4 v0 = *(const float4*)base;
        float4 m1 = (x4 > 0)  ? *(const float4*)(base - 4) : make_float4(0, 0, 0, 0);
        float4 p1 = (x4 < 31) ? *(const float4*)(base + 4) : make_float4(0, 0, 0, 0);
        float w[12] = {m1.x, m1.y, m1.z, m1.w,
                       v0.x, v0.y, v0.z, v0.w,
                       p1.x, p1.y, p1.z, p1.w};
        float o[4];
#pragma unroll
        for (int i = 0; i < 4; ++i) {
            o[i] = W3 * (w[i + 1] + w[i + 7]) + W2 * (w[i + 2] + w[i + 6])
                 + W1 * (w[i + 3] + w[i + 5]) + W0 * w[i + 4];
        }
        *(float4*)(S2 + (r << 7) + (x4 << 2)) = make_float4(o[0], o[1], o[2], o[3]);
    }
    __syncthreads();

    // Stage C: y-blur S2 -> global u2
    float* outp = u2 + (size_t)c * N + ((size_t)z << 14);
    for (int e = threadIdx.x; e < 32 * 32; e += 256) {
        int x4 = e & 31;
        int y  = e >> 5;
        const float* base = S2 + (y << 7) + (x4 << 2);
        float4 v0 = *(const float4*)(base);
        float4 v1 = *(const float4*)(base + (1 << 7));
        float4 v2 = *(const float4*)(base + (2 << 7));
        float4 v3 = *(const float4*)(base + (3 << 7));
        float4 v4 = *(const float4*)(base + (4 << 7));
        float4 v5 = *(const float4*)(base + (5 << 7));
        float4 v6 = *(const float4*)(base + (6 << 7));
        float4 acc;
        acc.x = W3 * (v0.x + v6.x) + W2 * (v1.x + v5.x) + W1 * (v2.x + v4.x) + W0 * v3.x;
        acc.y = W3 * (v0.y + v6.y) + W2 * (v1.y + v5.y) + W1 * (v2.y + v4.y) + W0 * v3.y;
        acc.z = W3 * (v0.z + v6.z) + W2 * (v1.z + v5.z) + W1 * (v2.z + v4.z) + W0 * v3.z;
        acc.w = W3 * (v0.w + v6.w) + W2 * (v1.w + v5.w) + W1 * (v2.w + v4.w) + W0 * v3.w;
        *(float4*)(outp + ((y0 + y) << 7) + (x4 << 2)) = acc;
    }
}

// ---------------------------------------------------------------------------
// z-blur, register sliding window. Each thread owns one (x,y) column for a
// 32-z chunk: 38 independent coalesced loads -> 32 outputs. No LDS/barriers.
// ---------------------------------------------------------------------------
__global__ __launch_bounds__(256) void z_blur_kernel(const float* __restrict__ in,
                                                     float* __restrict__ out) {
    int g = blockIdx.x * 256 + threadIdx.x;   // 0 .. 196607
    int col  = g & 16383;                     // (y<<7)|x
    int rest = g >> 14;                       // 0..11
    int zc = rest & 3;                        // z-chunk
    int c  = rest >> 2;                       // channel
    int z0 = zc << 5;
    const float* inp = in + (size_t)c * N + col;
    float* outp = out + (size_t)c * N + col;

    float win[38];
#pragma unroll
    for (int i = 0; i < 38; ++i) {
        int zz = z0 - 3 + i;
        win[i] = (zz >= 0 && zz < 128) ? inp[(size_t)zz << 14] : 0.0f;
    }
#pragma unroll
    for (int k = 0; k < 32; ++k) {
        float acc = W3 * (win[k] + win[k + 6]) + W2 * (win[k + 1] + win[k + 5])
                  + W1 * (win[k + 2] + win[k + 4]) + W0 * win[k + 3];
        outp[(size_t)(z0 + k) << 14] = acc;
    }
}

extern "C" void kernel_launch(void* const* d_in, const int* in_sizes, int n_in,
                              void* d_out, int out_size, void* d_ws, size_t ws_size,
                              hipStream_t stream) {
    const float* mov = (const float*)d_in[0];
    const float* fix = (const float*)d_in[1];
    float* vf = (float*)d_out;          // (3, N) — lives in d_out throughout
    float* ws = (float*)d_ws;
    float* warped = ws;                 // N floats
    float* u2     = ws + (size_t)N;     // 3N floats (xy-blurred forces)

    const int BLK = 256;
    const int gridW  = (N / 4) / BLK;      // 2048
    const int gridFX = 512 * 3;            // 1536
    const int gridZ  = (3 * N / 32) / BLK; // 768

    // Iteration 1: vf==0 => warped==moving; z_blur fully writes vf,
    // so no memset of d_out is needed.
    forces_xy_kernel<true><<<gridFX, BLK, 0, stream>>>(mov, fix, nullptr, u2);
    z_blur_kernel<<<gridZ, BLK, 0, stream>>>(u2, vf);

    for (int it = 1; it < ITERS; ++it) {
        warp_kernel<<<gridW, BLK, 0, stream>>>(mov, vf, warped);
        forces_xy_kernel<false><<<gridFX, BLK, 0, stream>>>(warped, fix, vf, u2);
        z_blur_kernel<<<gridZ, BLK, 0, stream>>>(u2, vf);
    }
}

// Round 6
// 1018.920 us; speedup vs baseline: 1.2504x; 1.2504x over previous
//
#include <hip/hip_runtime.h>

// Problem constants (match reference)
static constexpr int DIM = 128;
static constexpr int N = DIM * DIM * DIM;        // 2,097,152 voxels
static constexpr int ITERS = 20;
static constexpr float EPS = 1e-6f;

// Gaussian(sigma=1, radius=3) normalized weights
#define W0 0.39905028f
#define W1 0.24203624f
#define W2 0.05400559f
#define W3 0.00443305f

__device__ __forceinline__ int clamp_i(int v, int lo, int hi) {
    return min(max(v, lo), hi);
}

// ---------------------------------------------------------------------------
// Trilinear warp, 4 voxels/thread (proven R4 version).
// ---------------------------------------------------------------------------
__global__ __launch_bounds__(256) void warp_kernel(const float* __restrict__ mov,
                                                   const float* __restrict__ vf,
                                                   float* __restrict__ out) {
    int t = blockIdx.x * 256 + threadIdx.x;
    if (t >= N / 4) return;
    int idx = t << 2;
    int x0 = idx & 127, y = (idx >> 7) & 127, z = idx >> 14;

    float4 vz4 = *(const float4*)(vf + idx);
    float4 vy4 = *(const float4*)(vf + N + idx);
    float4 vx4 = *(const float4*)(vf + 2 * N + idx);
    float vzv[4] = {vz4.x, vz4.y, vz4.z, vz4.w};
    float vyv[4] = {vy4.x, vy4.y, vy4.z, vy4.w};
    float vxv[4] = {vx4.x, vx4.y, vx4.z, vx4.w};

    float o[4];
#pragma unroll
    for (int i = 0; i < 4; ++i) {
        float cz = (float)z + vzv[i];
        float cy = (float)y + vyv[i];
        float cx = (float)(x0 + i) + vxv[i];

        float flz = floorf(cz), fly = floorf(cy), flx = floorf(cx);
        float fz = cz - flz, fy = cy - fly, fx = cx - flx;

        int z0 = (int)flz, y0 = (int)fly, xx0 = (int)flx;
        int z0c = clamp_i(z0, 0, DIM - 1), z1c = clamp_i(z0 + 1, 0, DIM - 1);
        int y0c = clamp_i(y0, 0, DIM - 1), y1c = clamp_i(y0 + 1, 0, DIM - 1);
        int x0c = clamp_i(xx0, 0, DIM - 1), x1c = clamp_i(xx0 + 1, 0, DIM - 1);

        int b00 = (z0c << 14) + (y0c << 7);
        int b01 = (z0c << 14) + (y1c << 7);
        int b10 = (z1c << 14) + (y0c << 7);
        int b11 = (z1c << 14) + (y1c << 7);

        float v000 = mov[b00 + x0c], v001 = mov[b00 + x1c];
        float v010 = mov[b01 + x0c], v011 = mov[b01 + x1c];
        float v100 = mov[b10 + x0c], v101 = mov[b10 + x1c];
        float v110 = mov[b11 + x0c], v111 = mov[b11 + x1c];

        float c00 = v000 + fx * (v001 - v000);
        float c01 = v010 + fx * (v011 - v010);
        float c10 = v100 + fx * (v101 - v100);
        float c11 = v110 + fx * (v111 - v110);
        float c0 = c00 + fy * (c01 - c00);
        float c1 = c10 + fy * (c11 - c10);
        o[i] = c0 + fz * (c1 - c0);
    }
    *(float4*)(out + idx) = make_float4(o[0], o[1], o[2], o[3]);
}

// ---------------------------------------------------------------------------
// Fused forces (ALL 3 channels, computed ONCE per voxel) + x-blur + y-blur.
// One block per (z-plane, 16-row y-strip). Stage A: forces for the 22-row
// halo strip -> LDS S[3][22][128] (halo amp 1.375). Stage B: x-blur via
// register-held in-place LDS rewrite (read all -> barrier -> write all).
// Stage C: y-blur -> global u2 (3 channels). u is never materialized.
// LDS = 3*22*128*4 = 33792 B -> 4 blocks/CU.
// ---------------------------------------------------------------------------
#define ROWS 22            // 16 + 2*3 halo
#define SC(c, r) ((((c) * ROWS) + (r)) << 7)

template <bool FIRST>
__global__ __launch_bounds__(256) void forces_xy_kernel(const float* __restrict__ wpd,
                                                        const float* __restrict__ fix,
                                                        const float* __restrict__ vf,
                                                        float* __restrict__ u2) {
    int b = blockIdx.x;          // 1024 blocks
    int z = b & 127;
    int y0 = (b >> 7) << 4;      // 0,16,...,112

    __shared__ float S[3 * ROWS * 128];

    // ---- Stage A: forces (one eval/voxel, all channels) -> S
    for (int e = threadIdx.x; e < ROWS * 32; e += 256) {
        int x4 = e & 31;
        int r  = e >> 5;
        int gy = y0 + r - 3;
        float4 rz = make_float4(0, 0, 0, 0);
        float4 ry = make_float4(0, 0, 0, 0);
        float4 rx = make_float4(0, 0, 0, 0);
        if (gy >= 0 && gy < 128) {
            int idx = (z << 14) + (gy << 7) + (x4 << 2);
            int xb = x4 << 2;

            float4 wc4 = *(const float4*)(wpd + idx);
            float4 fc4 = *(const float4*)(fix + idx);

            int iyp = (gy < 127) ? idx + 128   : idx;
            int iym = (gy > 0)   ? idx - 128   : idx;
            int izp = (z < 127)  ? idx + 16384 : idx;
            int izm = (z > 0)    ? idx - 16384 : idx;

            float4 wyp = *(const float4*)(wpd + iyp), wym = *(const float4*)(wpd + iym);
            float4 wzp = *(const float4*)(wpd + izp), wzm = *(const float4*)(wpd + izm);
            float4 fyp = *(const float4*)(fix + iyp), fym = *(const float4*)(fix + iym);
            float4 fzp = *(const float4*)(fix + izp), fzm = *(const float4*)(fix + izm);

            float wl = (xb > 0)   ? wpd[idx - 1] : 0.0f;
            float wr = (xb < 124) ? wpd[idx + 4] : 0.0f;
            float fl = (xb > 0)   ? fix[idx - 1] : 0.0f;
            float fr = (xb < 124) ? fix[idx + 4] : 0.0f;

            float wcv[4] = {wc4.x, wc4.y, wc4.z, wc4.w};
            float fcv[4] = {fc4.x, fc4.y, fc4.z, fc4.w};
            float wypv[4] = {wyp.x, wyp.y, wyp.z, wyp.w};
            float wymv[4] = {wym.x, wym.y, wym.z, wym.w};
            float wzpv[4] = {wzp.x, wzp.y, wzp.z, wzp.w};
            float wzmv[4] = {wzm.x, wzm.y, wzm.z, wzm.w};
            float fypv[4] = {fyp.x, fyp.y, fyp.z, fyp.w};
            float fymv[4] = {fym.x, fym.y, fym.z, fym.w};
            float fzpv[4] = {fzp.x, fzp.y, fzp.z, fzp.w};
            float fzmv[4] = {fzm.x, fzm.y, fzm.z, fzm.w};

            float4 vz4 = FIRST ? make_float4(0, 0, 0, 0) : *(const float4*)(vf + idx);
            float4 vy4 = FIRST ? make_float4(0, 0, 0, 0) : *(const float4*)(vf + N + idx);
            float4 vx4 = FIRST ? make_float4(0, 0, 0, 0) : *(const float4*)(vf + 2 * N + idx);
            float vzv[4] = {vz4.x, vz4.y, vz4.z, vz4.w};
            float vyv[4] = {vy4.x, vy4.y, vy4.z, vy4.w};
            float vxv[4] = {vx4.x, vx4.y, vx4.z, vx4.w};

            float ozv[4], oyv[4], oxv[4];
#pragma unroll
            for (int i = 0; i < 4; ++i) {
                float wc = wcv[i], fc = fcv[i];
                float diff = wc - fc;

                float gwz = (z == 0)   ? (wzpv[i] - wc)
                          : (z == 127) ? (wc - wzmv[i])
                          : 0.5f * (wzpv[i] - wzmv[i]);
                float gfz = (z == 0)   ? (fzpv[i] - fc)
                          : (z == 127) ? (fc - fzmv[i])
                          : 0.5f * (fzpv[i] - fzmv[i]);
                float grz = 0.5f * (gwz + gfz);

                float gwy = (gy == 0)   ? (wypv[i] - wc)
                          : (gy == 127) ? (wc - wymv[i])
                          : 0.5f * (wypv[i] - wymv[i]);
                float gfy = (gy == 0)   ? (fypv[i] - fc)
                          : (gy == 127) ? (fc - fymv[i])
                          : 0.5f * (fypv[i] - fymv[i]);
                float gry = 0.5f * (gwy + gfy);

                float wleft  = (i == 0) ? wl : wcv[i - 1];
                float wright = (i == 3) ? wr : wcv[i + 1];
                float fleft  = (i == 0) ? fl : fcv[i - 1];
                float fright = (i == 3) ? fr : fcv[i + 1];
                int xi = xb + i;
                float gwx = (xi == 0)   ? (wright - wc)
                          : (xi == 127) ? (wc - wleft)
                          : 0.5f * (wright - wleft);
                float gfx = (xi == 0)   ? (fright - fc)
                          : (xi == 127) ? (fc - fleft)
                          : 0.5f * (fright - fleft);
                float grx = 0.5f * (gwx + gfx);

                float denom = grz * grz + gry * gry + grx * grx + diff * diff;
                float s = (denom > EPS) ? (diff / denom) : 0.0f;
                ozv[i] = vzv[i] + s * grz;
                oyv[i] = vyv[i] + s * gry;
                oxv[i] = vxv[i] + s * grx;
            }
            rz = make_float4(ozv[0], ozv[1], ozv[2], ozv[3]);
            ry = make_float4(oyv[0], oyv[1], oyv[2], oyv[3]);
            rx = make_float4(oxv[0], oxv[1], oxv[2], oxv[3]);
        }
        *(float4*)(S + SC(0, r) + (x4 << 2)) = rz;
        *(float4*)(S + SC(1, r) + (x4 << 2)) = ry;
        *(float4*)(S + SC(2, r) + (x4 << 2)) = rx;
    }
    __syncthreads();

    // ---- Stage B: x-blur, register-held in-place rewrite of S
    float4 xb[3][3];   // [unrolled e-iter][channel]
#pragma unroll
    for (int it = 0; it < 3; ++it) {
        int e = threadIdx.x + it * 256;
        if (e < ROWS * 32) {
            int x4 = e & 31;
            int r  = e >> 5;
#pragma unroll
            for (int c = 0; c < 3; ++c) {
                const float* base = S + SC(c, r) + (x4 << 2);
                float4 v0 = *(const float4*)base;
                float4 m1 = (x4 > 0)  ? *(const float4*)(base - 4) : make_float4(0, 0, 0, 0);
                float4 p1 = (x4 < 31) ? *(const float4*)(base + 4) : make_float4(0, 0, 0, 0);
                float w[12] = {m1.x, m1.y, m1.z, m1.w,
                               v0.x, v0.y, v0.z, v0.w,
                               p1.x, p1.y, p1.z, p1.w};
                float o[4];
#pragma unroll
                for (int i = 0; i < 4; ++i) {
                    o[i] = W3 * (w[i + 1] + w[i + 7]) + W2 * (w[i + 2] + w[i + 6])
                         + W1 * (w[i + 3] + w[i + 5]) + W0 * w[i + 4];
                }
                xb[it][c] = make_float4(o[0], o[1], o[2], o[3]);
            }
        }
    }
    __syncthreads();
#pragma unroll
    for (int it = 0; it < 3; ++it) {
        int e = threadIdx.x + it * 256;
        if (e < ROWS * 32) {
            int x4 = e & 31;
            int r  = e >> 5;
#pragma unroll
            for (int c = 0; c < 3; ++c)
                *(float4*)(S + SC(c, r) + (x4 << 2)) = xb[it][c];
        }
    }
    __syncthreads();

    // ---- Stage C: y-blur S -> global u2 (16 rows x 32 float4 x 3 ch)
    for (int e = threadIdx.x; e < 16 * 32 * 3; e += 256) {
        int x4 = e & 31;
        int t2 = e >> 5;
        int y  = t2 & 15;
        int c  = t2 >> 4;
        const float* base = S + SC(c, y) + (x4 << 2);   // rows y..y+6 (halo offset)
        float4 v0 = *(const float4*)(base);
        float4 v1 = *(const float4*)(base + (1 << 7));
        float4 v2 = *(const float4*)(base + (2 << 7));
        float4 v3 = *(const float4*)(base + (3 << 7));
        float4 v4 = *(const float4*)(base + (4 << 7));
        float4 v5 = *(const float4*)(base + (5 << 7));
        float4 v6 = *(const float4*)(base + (6 << 7));
        float4 acc;
        acc.x = W3 * (v0.x + v6.x) + W2 * (v1.x + v5.x) + W1 * (v2.x + v4.x) + W0 * v3.x;
        acc.y = W3 * (v0.y + v6.y) + W2 * (v1.y + v5.y) + W1 * (v2.y + v4.y) + W0 * v3.y;
        acc.z = W3 * (v0.z + v6.z) + W2 * (v1.z + v5.z) + W1 * (v2.z + v4.z) + W0 * v3.z;
        acc.w = W3 * (v0.w + v6.w) + W2 * (v1.w + v5.w) + W1 * (v2.w + v4.w) + W0 * v3.w;
        *(float4*)(u2 + (size_t)c * N + ((size_t)z << 14) + ((y0 + y) << 7) + (x4 << 2)) = acc;
    }
}

// ---------------------------------------------------------------------------
// z-blur, register sliding window (proven R4 version).
// ---------------------------------------------------------------------------
__global__ __launch_bounds__(256) void z_blur_kernel(const float* __restrict__ in,
                                                     float* __restrict__ out) {
    int g = blockIdx.x * 256 + threadIdx.x;   // 0 .. 196607
    int col  = g & 16383;                     // (y<<7)|x
    int rest = g >> 14;                       // 0..11
    int zc = rest & 3;                        // z-chunk
    int c  = rest >> 2;                       // channel
    int z0 = zc << 5;
    const float* inp = in + (size_t)c * N + col;
    float* outp = out + (size_t)c * N + col;

    float win[38];
#pragma unroll
    for (int i = 0; i < 38; ++i) {
        int zz = z0 - 3 + i;
        win[i] = (zz >= 0 && zz < 128) ? inp[(size_t)zz << 14] : 0.0f;
    }
#pragma unroll
    for (int k = 0; k < 32; ++k) {
        float acc = W3 * (win[k] + win[k + 6]) + W2 * (win[k + 1] + win[k + 5])
                  + W1 * (win[k + 2] + win[k + 4]) + W0 * win[k + 3];
        outp[(size_t)(z0 + k) << 14] = acc;
    }
}

extern "C" void kernel_launch(void* const* d_in, const int* in_sizes, int n_in,
                              void* d_out, int out_size, void* d_ws, size_t ws_size,
                              hipStream_t stream) {
    const float* mov = (const float*)d_in[0];
    const float* fix = (const float*)d_in[1];
    float* vf = (float*)d_out;          // (3, N) — lives in d_out throughout
    float* ws = (float*)d_ws;
    float* warped = ws;                 // N floats
    float* u2     = ws + (size_t)N;     // 3N floats (xy-blurred forces)

    const int BLK = 256;
    const int gridW  = (N / 4) / BLK;      // 2048
    const int gridFX = 128 * 8;            // 1024 (z-plane x y-strip)
    const int gridZ  = (3 * N / 32) / BLK; // 768

    // Iteration 1: vf==0 => warped==moving; z_blur fully writes vf,
    // so no memset of d_out is needed.
    forces_xy_kernel<true><<<gridFX, BLK, 0, stream>>>(mov, fix, nullptr, u2);
    z_blur_kernel<<<gridZ, BLK, 0, stream>>>(u2, vf);

    for (int it = 1; it < ITERS; ++it) {
        warp_kernel<<<gridW, BLK, 0, stream>>>(mov, vf, warped);
        forces_xy_kernel<false><<<gridFX, BLK, 0, stream>>>(warped, fix, vf, u2);
        z_blur_kernel<<<gridZ, BLK, 0, stream>>>(u2, vf);
    }
}

// Round 7
// 887.708 us; speedup vs baseline: 1.4353x; 1.1478x over previous
//
#include <hip/hip_runtime.h>

// Problem constants (match reference)
static constexpr int DIM = 128;
static constexpr int N = DIM * DIM * DIM;        // 2,097,152 voxels
static constexpr int ITERS = 20;
static constexpr float EPS = 1e-6f;

// Gaussian(sigma=1, radius=3) normalized weights
#define W0 0.39905028f
#define W1 0.24203624f
#define W2 0.05400559f
#define W3 0.00443305f

__device__ __forceinline__ int clamp_i(int v, int lo, int hi) {
    return min(max(v, lo), hi);
}

// ---------------------------------------------------------------------------
// Fused forces (ALL 3 channels, computed ONCE per voxel) + x-blur + y-blur.
// One block per (z-plane, 16-row y-strip). Stage A: forces for the 22-row
// halo strip -> LDS S[3][22][128] (halo amp 1.375). Stage B: x-blur via
// register-held in-place LDS rewrite. Stage C: y-blur -> global u2.
// u is never materialized. LDS = 3*22*128*4 = 33792 B -> 4 blocks/CU.
// (Proven R6 structure, unchanged.)
// ---------------------------------------------------------------------------
#define ROWS 22            // 16 + 2*3 halo
#define SC(c, r) ((((c) * ROWS) + (r)) << 7)

template <bool FIRST>
__global__ __launch_bounds__(256) void forces_xy_kernel(const float* __restrict__ wpd,
                                                        const float* __restrict__ fix,
                                                        const float* __restrict__ vf,
                                                        float* __restrict__ u2) {
    int b = blockIdx.x;          // 1024 blocks
    int z = b & 127;
    int y0 = (b >> 7) << 4;      // 0,16,...,112

    __shared__ float S[3 * ROWS * 128];

    // ---- Stage A: forces (one eval/voxel, all channels) -> S
    for (int e = threadIdx.x; e < ROWS * 32; e += 256) {
        int x4 = e & 31;
        int r  = e >> 5;
        int gy = y0 + r - 3;
        float4 rz = make_float4(0, 0, 0, 0);
        float4 ry = make_float4(0, 0, 0, 0);
        float4 rx = make_float4(0, 0, 0, 0);
        if (gy >= 0 && gy < 128) {
            int idx = (z << 14) + (gy << 7) + (x4 << 2);
            int xb = x4 << 2;

            float4 wc4 = *(const float4*)(wpd + idx);
            float4 fc4 = *(const float4*)(fix + idx);

            int iyp = (gy < 127) ? idx + 128   : idx;
            int iym = (gy > 0)   ? idx - 128   : idx;
            int izp = (z < 127)  ? idx + 16384 : idx;
            int izm = (z > 0)    ? idx - 16384 : idx;

            float4 wyp = *(const float4*)(wpd + iyp), wym = *(const float4*)(wpd + iym);
            float4 wzp = *(const float4*)(wpd + izp), wzm = *(const float4*)(wpd + izm);
            float4 fyp = *(const float4*)(fix + iyp), fym = *(const float4*)(fix + iym);
            float4 fzp = *(const float4*)(fix + izp), fzm = *(const float4*)(fix + izm);

            float wl = (xb > 0)   ? wpd[idx - 1] : 0.0f;
            float wr = (xb < 124) ? wpd[idx + 4] : 0.0f;
            float fl = (xb > 0)   ? fix[idx - 1] : 0.0f;
            float fr = (xb < 124) ? fix[idx + 4] : 0.0f;

            float wcv[4] = {wc4.x, wc4.y, wc4.z, wc4.w};
            float fcv[4] = {fc4.x, fc4.y, fc4.z, fc4.w};
            float wypv[4] = {wyp.x, wyp.y, wyp.z, wyp.w};
            float wymv[4] = {wym.x, wym.y, wym.z, wym.w};
            float wzpv[4] = {wzp.x, wzp.y, wzp.z, wzp.w};
            float wzmv[4] = {wzm.x, wzm.y, wzm.z, wzm.w};
            float fypv[4] = {fyp.x, fyp.y, fyp.z, fyp.w};
            float fymv[4] = {fym.x, fym.y, fym.z, fym.w};
            float fzpv[4] = {fzp.x, fzp.y, fzp.z, fzp.w};
            float fzmv[4] = {fzm.x, fzm.y, fzm.z, fzm.w};

            float4 vz4 = FIRST ? make_float4(0, 0, 0, 0) : *(const float4*)(vf + idx);
            float4 vy4 = FIRST ? make_float4(0, 0, 0, 0) : *(const float4*)(vf + N + idx);
            float4 vx4 = FIRST ? make_float4(0, 0, 0, 0) : *(const float4*)(vf + 2 * N + idx);
            float vzv[4] = {vz4.x, vz4.y, vz4.z, vz4.w};
            float vyv[4] = {vy4.x, vy4.y, vy4.z, vy4.w};
            float vxv[4] = {vx4.x, vx4.y, vx4.z, vx4.w};

            float ozv[4], oyv[4], oxv[4];
#pragma unroll
            for (int i = 0; i < 4; ++i) {
                float wc = wcv[i], fc = fcv[i];
                float diff = wc - fc;

                float gwz = (z == 0)   ? (wzpv[i] - wc)
                          : (z == 127) ? (wc - wzmv[i])
                          : 0.5f * (wzpv[i] - wzmv[i]);
                float gfz = (z == 0)   ? (fzpv[i] - fc)
                          : (z == 127) ? (fc - fzmv[i])
                          : 0.5f * (fzpv[i] - fzmv[i]);
                float grz = 0.5f * (gwz + gfz);

                float gwy = (gy == 0)   ? (wypv[i] - wc)
                          : (gy == 127) ? (wc - wymv[i])
                          : 0.5f * (wypv[i] - wymv[i]);
                float gfy = (gy == 0)   ? (fypv[i] - fc)
                          : (gy == 127) ? (fc - fymv[i])
                          : 0.5f * (fypv[i] - fymv[i]);
                float gry = 0.5f * (gwy + gfy);

                float wleft  = (i == 0) ? wl : wcv[i - 1];
                float wright = (i == 3) ? wr : wcv[i + 1];
                float fleft  = (i == 0) ? fl : fcv[i - 1];
                float fright = (i == 3) ? fr : fcv[i + 1];
                int xi = xb + i;
                float gwx = (xi == 0)   ? (wright - wc)
                          : (xi == 127) ? (wc - wleft)
                          : 0.5f * (wright - wleft);
                float gfx = (xi == 0)   ? (fright - fc)
                          : (xi == 127) ? (fc - fleft)
                          : 0.5f * (fright - fleft);
                float grx = 0.5f * (gwx + gfx);

                float denom = grz * grz + gry * gry + grx * grx + diff * diff;
                float s = (denom > EPS) ? (diff / denom) : 0.0f;
                ozv[i] = vzv[i] + s * grz;
                oyv[i] = vyv[i] + s * gry;
                oxv[i] = vxv[i] + s * grx;
            }
            rz = make_float4(ozv[0], ozv[1], ozv[2], ozv[3]);
            ry = make_float4(oyv[0], oyv[1], oyv[2], oyv[3]);
            rx = make_float4(oxv[0], oxv[1], oxv[2], oxv[3]);
        }
        *(float4*)(S + SC(0, r) + (x4 << 2)) = rz;
        *(float4*)(S + SC(1, r) + (x4 << 2)) = ry;
        *(float4*)(S + SC(2, r) + (x4 << 2)) = rx;
    }
    __syncthreads();

    // ---- Stage B: x-blur, register-held in-place rewrite of S
    float4 xb[3][3];   // [unrolled e-iter][channel]
#pragma unroll
    for (int it = 0; it < 3; ++it) {
        int e = threadIdx.x + it * 256;
        if (e < ROWS * 32) {
            int x4 = e & 31;
            int r  = e >> 5;
#pragma unroll
            for (int c = 0; c < 3; ++c) {
                const float* base = S + SC(c, r) + (x4 << 2);
                float4 v0 = *(const float4*)base;
                float4 m1 = (x4 > 0)  ? *(const float4*)(base - 4) : make_float4(0, 0, 0, 0);
                float4 p1 = (x4 < 31) ? *(const float4*)(base + 4) : make_float4(0, 0, 0, 0);
                float w[12] = {m1.x, m1.y, m1.z, m1.w,
                               v0.x, v0.y, v0.z, v0.w,
                               p1.x, p1.y, p1.z, p1.w};
                float o[4];
#pragma unroll
                for (int i = 0; i < 4; ++i) {
                    o[i] = W3 * (w[i + 1] + w[i + 7]) + W2 * (w[i + 2] + w[i + 6])
                         + W1 * (w[i + 3] + w[i + 5]) + W0 * w[i + 4];
                }
                xb[it][c] = make_float4(o[0], o[1], o[2], o[3]);
            }
        }
    }
    __syncthreads();
#pragma unroll
    for (int it = 0; it < 3; ++it) {
        int e = threadIdx.x + it * 256;
        if (e < ROWS * 32) {
            int x4 = e & 31;
            int r  = e >> 5;
#pragma unroll
            for (int c = 0; c < 3; ++c)
                *(float4*)(S + SC(c, r) + (x4 << 2)) = xb[it][c];
        }
    }
    __syncthreads();

    // ---- Stage C: y-blur S -> global u2 (16 rows x 32 float4 x 3 ch)
    for (int e = threadIdx.x; e < 16 * 32 * 3; e += 256) {
        int x4 = e & 31;
        int t2 = e >> 5;
        int y  = t2 & 15;
        int c  = t2 >> 4;
        const float* base = S + SC(c, y) + (x4 << 2);   // rows y..y+6 (halo offset)
        float4 v0 = *(const float4*)(base);
        float4 v1 = *(const float4*)(base + (1 << 7));
        float4 v2 = *(const float4*)(base + (2 << 7));
        float4 v3 = *(const float4*)(base + (3 << 7));
        float4 v4 = *(const float4*)(base + (4 << 7));
        float4 v5 = *(const float4*)(base + (5 << 7));
        float4 v6 = *(const float4*)(base + (6 << 7));
        float4 acc;
        acc.x = W3 * (v0.x + v6.x) + W2 * (v1.x + v5.x) + W1 * (v2.x + v4.x) + W0 * v3.x;
        acc.y = W3 * (v0.y + v6.y) + W2 * (v1.y + v5.y) + W1 * (v2.y + v4.y) + W0 * v3.y;
        acc.z = W3 * (v0.z + v6.z) + W2 * (v1.z + v5.z) + W1 * (v2.z + v4.z) + W0 * v3.z;
        acc.w = W3 * (v0.w + v6.w) + W2 * (v1.w + v5.w) + W1 * (v2.w + v4.w) + W0 * v3.w;
        *(float4*)(u2 + (size_t)c * N + ((size_t)z << 14) + ((y0 + y) << 7) + (x4 << 2)) = acc;
    }
}

// ---------------------------------------------------------------------------
// Fused z-blur + (next iteration's) trilinear warp. One thread owns an (x,y)
// column x 16-z chunk for ALL 3 channels: 3x22-tap register windows -> 48
// blurred vf values -> write vf; then warp those 16 voxels (vf already in
// registers - no global vf re-read) -> write warped. DO_WARP=false for the
// final iteration (warp result unused).
// Grid: 16384 cols x 8 chunks = 131072 threads = 512 blocks x 256.
// ---------------------------------------------------------------------------
template <bool DO_WARP>
__global__ __launch_bounds__(256) void zblur_warp_kernel(const float* __restrict__ u2,
                                                         const float* __restrict__ mov,
                                                         float* __restrict__ vf,
                                                         float* __restrict__ warped) {
    int g = blockIdx.x * 256 + threadIdx.x;   // 0 .. 131071
    int col = g & 16383;                      // (y<<7)|x
    int zc  = g >> 14;                        // 0..7
    int z0  = zc << 4;
    int x = col & 127, y = col >> 7;

    float bz[3][16];
#pragma unroll
    for (int c = 0; c < 3; ++c) {
        const float* inp = u2 + (size_t)c * N + col;
        float win[22];
#pragma unroll
        for (int i = 0; i < 22; ++i) {
            int zz = z0 - 3 + i;
            win[i] = (zz >= 0 && zz < 128) ? inp[(size_t)zz << 14] : 0.0f;
        }
#pragma unroll
        for (int k = 0; k < 16; ++k) {
            bz[c][k] = W3 * (win[k] + win[k + 6]) + W2 * (win[k + 1] + win[k + 5])
                     + W1 * (win[k + 2] + win[k + 4]) + W0 * win[k + 3];
        }
        float* outp = vf + (size_t)c * N + col;
#pragma unroll
        for (int k = 0; k < 16; ++k)
            outp[(size_t)(z0 + k) << 14] = bz[c][k];
    }

    if (DO_WARP) {
        for (int k = 0; k < 16; ++k) {
            int z = z0 + k;
            float cz = (float)z + bz[0][k];
            float cy = (float)y + bz[1][k];
            float cx = (float)x + bz[2][k];

            float flz = floorf(cz), fly = floorf(cy), flx = floorf(cx);
            float fz = cz - flz, fy = cy - fly, fx = cx - flx;

            int zi = (int)flz, yi = (int)fly, xi = (int)flx;
            int z0c = clamp_i(zi, 0, DIM - 1), z1c = clamp_i(zi + 1, 0, DIM - 1);
            int y0c = clamp_i(yi, 0, DIM - 1), y1c = clamp_i(yi + 1, 0, DIM - 1);
            int x0c = clamp_i(xi, 0, DIM - 1), x1c = clamp_i(xi + 1, 0, DIM - 1);

            int b00 = (z0c << 14) + (y0c << 7);
            int b01 = (z0c << 14) + (y1c << 7);
            int b10 = (z1c << 14) + (y0c << 7);
            int b11 = (z1c << 14) + (y1c << 7);

            float v000 = mov[b00 + x0c], v001 = mov[b00 + x1c];
            float v010 = mov[b01 + x0c], v011 = mov[b01 + x1c];
            float v100 = mov[b10 + x0c], v101 = mov[b10 + x1c];
            float v110 = mov[b11 + x0c], v111 = mov[b11 + x1c];

            float c00 = v000 + fx * (v001 - v000);
            float c01 = v010 + fx * (v011 - v010);
            float c10 = v100 + fx * (v101 - v100);
            float c11 = v110 + fx * (v111 - v110);
            float c0 = c00 + fy * (c01 - c00);
            float c1 = c10 + fy * (c11 - c10);
            warped[((size_t)z << 14) + col] = c0 + fz * (c1 - c0);
        }
    }
}

extern "C" void kernel_launch(void* const* d_in, const int* in_sizes, int n_in,
                              void* d_out, int out_size, void* d_ws, size_t ws_size,
                              hipStream_t stream) {
    const float* mov = (const float*)d_in[0];
    const float* fix = (const float*)d_in[1];
    float* vf = (float*)d_out;          // (3, N) — lives in d_out throughout
    float* ws = (float*)d_ws;
    float* warped = ws;                 // N floats
    float* u2     = ws + (size_t)N;     // 3N floats (xy-blurred forces)

    const int BLK = 256;
    const int gridFX = 128 * 8;            // 1024 (z-plane x y-strip)
    const int gridZW = (N / 16) / BLK;     // 512

    // Iteration 1: vf==0 => warped==moving (use mov directly); zblur_warp
    // fully writes vf, so no memset of d_out is needed.
    forces_xy_kernel<true><<<gridFX, BLK, 0, stream>>>(mov, fix, nullptr, u2);
    zblur_warp_kernel<true><<<gridZW, BLK, 0, stream>>>(u2, mov, vf, warped);

    for (int it = 1; it < ITERS - 1; ++it) {
        forces_xy_kernel<false><<<gridFX, BLK, 0, stream>>>(warped, fix, vf, u2);
        zblur_warp_kernel<true><<<gridZW, BLK, 0, stream>>>(u2, mov, vf, warped);
    }
    // Final iteration: no warp needed (result unused).
    forces_xy_kernel<false><<<gridFX, BLK, 0, stream>>>(warped, fix, vf, u2);
    zblur_warp_kernel<false><<<gridZW, BLK, 0, stream>>>(u2, mov, vf, warped);
}